// Round 5
// baseline (6461.455 us; speedup 1.0000x reference)
//
#include <hip/hip_runtime.h>
#include <math.h>

typedef _Float16 f16;
typedef _Float16 f16x8 __attribute__((ext_vector_type(8)));
typedef _Float16 f16x4 __attribute__((ext_vector_type(4)));
typedef float f32x4 __attribute__((ext_vector_type(4)));

#define NS     512
#define NG     1024
#define NV     90

// LDS map for rnn_chunk (bytes):
//   [0, 16384)      : h double buffer, 2 x 16 rows x 256 f16 (XOR-swizzled, 32-granule)
//   [16384, 159744) : per-wave LDS-resident weight frags: wave w at 16384 + w*35840
#define R_LDS_BYTES 159744

__device__ __forceinline__ float sgf(float x) {
    return __builtin_amdgcn_rcpf(1.f + exp2f(-1.44269504089f * x));
}
__device__ __forceinline__ float thf(float x) {
    return 2.f * __builtin_amdgcn_rcpf(1.f + exp2f(-2.88539008178f * x)) - 1.f;
}

// frag id f = (jt*4+g)*8 + kt. 93 frags in regs, 35 in LDS.
__device__ __forceinline__ bool in_lds_f(int f) {
    return ((f & 7) >= 6) || (f >= 123);
}
__device__ __forceinline__ int reg_idx_f(int f) {
    return (f >> 3) * 6 + (f & 7);
}
__device__ __forceinline__ int lds_idx_f(int f) {
    int kt = f & 7;
    return (kt >= 6) ? ((f >> 3) * 2 + (kt - 6)) : (32 + (kt - 3));
}

// ---------------- setup kernels ----------------

// T0p[v][w][jt][l15][g] f16 = sum_e emb[v][e]*Wih0[n][e] + bih0[n]+bhh0[n],
// n = g*256 + w*64 + jt*16 + l15
__global__ void build_t0p(const float* __restrict__ emb, const float* __restrict__ wih0,
                          const float* __restrict__ bih0, const float* __restrict__ bhh0,
                          f16* __restrict__ t0p) {
    int v = blockIdx.x, tid = threadIdx.x;
    int w = tid >> 6, jt = (tid >> 4) & 3, l15 = tid & 15;
    __shared__ float e[8];
    if (tid < 8) e[tid] = emb[v * 8 + tid];
    __syncthreads();
    f16x4 o;
    #pragma unroll
    for (int g = 0; g < 4; ++g) {
        int n = g * 256 + w * 64 + jt * 16 + l15;
        float s = bih0[n] + bhh0[n];
        #pragma unroll
        for (int k = 0; k < 8; ++k) s += e[k] * wih0[n * 8 + k];
        o[g] = (f16)s;
    }
    *(f16x4*)&t0p[((((size_t)v * 4 + w) * 4 + jt) * 16 + l15) * 4] = o;
}

// pack 1024x256 f32 weight into B-frag layout Wp[(w*128+f)*64+l][8]
__global__ void pack_rw(const float* __restrict__ W, f16* __restrict__ Wp) {
    int gid = blockIdx.x * 256 + threadIdx.x;   // 32768
    int l = gid & 63, f = (gid >> 6) & 127, w = gid >> 13;
    int kt = f & 7, g = (f >> 3) & 3, jt = f >> 5;
    int n = g * 256 + w * 64 + jt * 16 + (l & 15);
    int k = kt * 32 + (l >> 4) * 8;
    f16x8 v;
    #pragma unroll
    for (int e = 0; e < 8; ++e) v[e] = (f16)W[n * 256 + k + e];
    *(f16x8*)&Wp[(size_t)gid * 8] = v;
}

// pack Wfc (90x256) zero-padded to 96 rows: Wfcp[(nt*8+kt)*64+l][8]
__global__ void pack_fc(const float* __restrict__ Wfc, f16* __restrict__ Wp) {
    int gid = blockIdx.x * 256 + threadIdx.x;   // 3072
    int l = gid & 63, kt = (gid >> 6) & 7, nt = gid >> 9;
    int n = nt * 16 + (l & 15);
    int k = kt * 32 + (l >> 4) * 8;
    f16x8 v;
    #pragma unroll
    for (int e = 0; e < 8; ++e) v[e] = (n < NV) ? (f16)Wfc[n * 256 + k + e] : (f16)0.f;
    *(f16x8*)&Wp[(size_t)gid * 8] = v;
}

// ---------------- recurrent chunk kernel (both layers) ----------------
// grid 16 (batch groups of 16 rows), block 256 (4 waves, 1/SIMD).
// Wave w owns hidden slice j in [w*64, w*64+64) -> gate rows {g*256+j}.
// Weights: 93 frags pinned in VGPRs (asm barrier prevents remat), 35 in LDS.
// Runs steps t0..t0+tc-1; state (c,h) persists in cst/hst between chunks.
template<int LAYER>
__launch_bounds__(256, 1)
__global__ void rnn_chunk(const f16* __restrict__ Wp, const int* __restrict__ x,
                          const f16* __restrict__ T0p, const f16* __restrict__ xgc,
                          f16* __restrict__ hdump, float* __restrict__ cst,
                          f16* __restrict__ hst, int t0, int tc) {
    extern __shared__ char smem[];
    f16* hb = (f16*)smem;   // 2 x 4096 f16
    const int tid = threadIdx.x;
    const int w = tid >> 6, l = tid & 63, l15 = l & 15, lq = l >> 4;
    const int bg = blockIdx.x;

    const f16* wgl = Wp + ((size_t)w * 128) * 512 + l * 8;   // frag f at +f*512 (f16)
    f16* wlds = (f16*)(smem + 16384 + w * 35840);

    // stage LDS-resident frags
    #pragma unroll
    for (int fi = 0; fi < 35; ++fi) {
        int f = (fi < 32) ? ((fi >> 1) * 8 + 6 + (fi & 1)) : (123 + (fi - 32));
        *(f16x8*)&wlds[fi * 512 + l * 8] = *(const f16x8*)&wgl[(size_t)f * 512];
    }
    // preload register frags and PIN them (asm round-trip prevents the compiler
    // from rematerializing these as per-use global reloads: R3 showed VGPR=252,
    // i.e. the preload had been demoted to 93 global loads/step/wave)
    f32x4 w_r[93];
    #pragma unroll
    for (int f = 0; f < 128; ++f)
        if (!in_lds_f(f))
            w_r[reg_idx_f(f)] = *(const f32x4*)&wgl[(size_t)f * 512];
    #pragma unroll
    for (int i = 0; i < 93; ++i) {
        float a0 = w_r[i][0], a1 = w_r[i][1], a2 = w_r[i][2], a3 = w_r[i][3];
        asm volatile("" : "+v"(a0), "+v"(a1), "+v"(a2), "+v"(a3));
        w_r[i][0] = a0; w_r[i][1] = a1; w_r[i][2] = a2; w_r[i][3] = a3;
    }

    float c[16];
    if (t0 == 0) {
        #pragma unroll
        for (int i = 0; i < 16; ++i) hb[i * 256 + tid] = (f16)0.f;
        #pragma unroll
        for (int i = 0; i < 16; ++i) c[i] = 0.f;
    } else {
        // restore h state into buffer 0 (raw 8KB blob) and c state
        const char* hsrc = (const char*)hst + (size_t)bg * 8192 + tid * 32;
        *(uint4*)(smem + tid * 32)      = *(const uint4*)hsrc;
        *(uint4*)(smem + tid * 32 + 16) = *(const uint4*)(hsrc + 16);
        const float* cp = cst + (((size_t)bg * 4 + w) * 64 + l) * 16;
        #pragma unroll
        for (int i = 0; i < 16; ++i) c[i] = cp[i];
    }
    __syncthreads();

    const int hswz = 32 * (l15 & 7);

    for (int s = 0; s < tc; ++s) {
        const int t = t0 + s;
        const int rb = (s & 1) * 4096, wb = rb ^ 4096;

        // dump h(t-1) (raw swizzled blob) - fire and forget
        if (s > 0) {
            const char* src = smem + rb * 2 + tid * 32;
            uint4 d0 = *(const uint4*)src;
            uint4 d1 = *(const uint4*)(src + 16);
            f16* dst = hdump + (((size_t)(s - 1) * 16 + bg) << 12) + tid * 16;
            *(uint4*)dst = d0;
            *((uint4*)dst + 1) = d1;
        }

        int xv[4];
        if constexpr (LAYER == 0) {
            #pragma unroll
            for (int r = 0; r < 4; ++r)
                xv[r] = x[(bg * 16 + lq * 4 + r) * NS + t];
        }

        uint4 ivq[2][2];
        f16x4 iv0[2][4];
        // preload chunk 0's input-gate contribution
        if constexpr (LAYER == 0) {
            #pragma unroll
            for (int r = 0; r < 4; ++r)
                iv0[0][r] = *(const f16x4*)&T0p[((((size_t)xv[r] * 4 + w) * 4 + 0) * 16 + l15) * 4];
        } else {
            const f16* p_ = xgc + (((size_t)(s * 16 + bg) * 16) + w * 4 + 0) * 1024 + l * 16;
            ivq[0][0] = *(const uint4*)p_;
            ivq[0][1] = *(const uint4*)(p_ + 8);
        }

        // A-fragments of h(t-1): depend only on kt -> load ONCE per step (was 4x)
        f16x8 a[8];
        #pragma unroll
        for (int kt = 0; kt < 8; ++kt)
            a[kt] = *(const f16x8*)&hb[rb + l15 * 256 + ((kt * 32 + lq * 8) ^ hswz)];

        #pragma unroll
        for (int jt = 0; jt < 4; ++jt) {
            const int cs = jt & 1, nx = cs ^ 1;
            if (jt < 3) {   // prefetch next chunk's contribution
                if constexpr (LAYER == 0) {
                    #pragma unroll
                    for (int r = 0; r < 4; ++r)
                        iv0[nx][r] = *(const f16x4*)&T0p[((((size_t)xv[r] * 4 + w) * 4 + (jt + 1)) * 16 + l15) * 4];
                } else {
                    const f16* p_ = xgc + (((size_t)(s * 16 + bg) * 16) + w * 4 + (jt + 1)) * 1024 + l * 16;
                    ivq[nx][0] = *(const uint4*)p_;
                    ivq[nx][1] = *(const uint4*)(p_ + 8);
                }
            }

            f32x4 acc[4];
            #pragma unroll
            for (int g = 0; g < 4; ++g) acc[g] = (f32x4){0.f, 0.f, 0.f, 0.f};

            #pragma unroll
            for (int kt = 0; kt < 8; ++kt) {
                #pragma unroll
                for (int g = 0; g < 4; ++g) {
                    const int f = (jt * 4 + g) * 8 + kt;
                    f16x8 bfr;
                    if (in_lds_f(f)) bfr = *(const f16x8*)&wlds[lds_idx_f(f) * 512 + l * 8];
                    else             bfr = __builtin_bit_cast(f16x8, w_r[reg_idx_f(f)]);
                    acc[g] = __builtin_amdgcn_mfma_f32_16x16x32_f16(a[kt], bfr, acc[g], 0, 0, 0);
                }
            }

            const f16* ivf = (const f16*)&ivq[cs][0];
            #pragma unroll
            for (int r = 0; r < 4; ++r) {
                float gi, gf, gg, go;
                if constexpr (LAYER == 0) {
                    gi = acc[0][r] + (float)iv0[cs][r][0];
                    gf = acc[1][r] + (float)iv0[cs][r][1];
                    gg = acc[2][r] + (float)iv0[cs][r][2];
                    go = acc[3][r] + (float)iv0[cs][r][3];
                } else {
                    gi = acc[0][r] + (float)ivf[0 * 4 + r];
                    gf = acc[1][r] + (float)ivf[1 * 4 + r];
                    gg = acc[2][r] + (float)ivf[2 * 4 + r];
                    go = acc[3][r] + (float)ivf[3 * 4 + r];
                }
                float si = sgf(gi), sf = sgf(gf), tg = thf(gg), so = sgf(go);
                const int ci = jt * 4 + r;
                c[ci] = sf * c[ci] + si * tg;
                float h = so * thf(c[ci]);
                const int b = lq * 4 + r;
                hb[wb + b * 256 + ((w * 64 + jt * 16 + l15) ^ (32 * (b & 7)))] = (f16)h;
            }
        }
        __syncthreads();
    }
    // epilogue: final h lives in buffer 0 (tc even). dump it + save state.
    {
        const char* src = smem + tid * 32;
        uint4 d0 = *(const uint4*)src;
        uint4 d1 = *(const uint4*)(src + 16);
        f16* dst = hdump + (((size_t)(tc - 1) * 16 + bg) << 12) + tid * 16;
        *(uint4*)dst = d0;
        *((uint4*)dst + 1) = d1;
        char* hdst = (char*)hst + (size_t)bg * 8192 + tid * 32;
        *(uint4*)hdst = d0;
        *(uint4*)(hdst + 16) = d1;
        float* cp = cst + (((size_t)bg * 4 + w) * 64 + l) * 16;
        #pragma unroll
        for (int i = 0; i < 16; ++i) cp[i] = c[i];
    }
}

// ---------------- xg1 = Wih1 @ h1 + (bih1+bhh1), frag-layout output (chunk) -----
// grid: 16(bg) x 4(ns) x (tc/16). block 256: wave wv owns jt=wv.
__launch_bounds__(256, 1)
__global__ void xg1_gemm(const f16* __restrict__ h1c, const f16* __restrict__ Wxp,
                         const float* __restrict__ bih1, const float* __restrict__ bhh1,
                         f16* __restrict__ xgc) {
    const int tid = threadIdx.x, wv = tid >> 6, l = tid & 63, l15 = l & 15, lq = l >> 4;
    const int bid = blockIdx.x, bg = bid & 15, ns = (bid >> 4) & 3, tcc = bid >> 6;

    f16x8 bf[4][8];
    #pragma unroll
    for (int g = 0; g < 4; ++g)
        #pragma unroll
        for (int kt = 0; kt < 8; ++kt)
            bf[g][kt] = *(const f16x8*)&Wxp[((size_t)(ns * 128 + (wv * 4 + g) * 8 + kt) * 64 + l) * 8];
    float bs[4];
    #pragma unroll
    for (int g = 0; g < 4; ++g) {
        int n = g * 256 + ns * 64 + wv * 16 + l15;
        bs[g] = bih1[n] + bhh1[n];
    }
    const int hswz = 32 * (l15 & 7);

    for (int tt = 0; tt < 16; ++tt) {
        int s = tcc * 16 + tt;
        const f16* blob = h1c + ((size_t)(s * 16 + bg) << 12);
        f16x8 a[8];
        #pragma unroll
        for (int kt = 0; kt < 8; ++kt)
            a[kt] = *(const f16x8*)&blob[l15 * 256 + ((kt * 32 + lq * 8) ^ hswz)];
        f32x4 acc[4];
        #pragma unroll
        for (int g = 0; g < 4; ++g) acc[g] = (f32x4){bs[g], bs[g], bs[g], bs[g]};
        #pragma unroll
        for (int kt = 0; kt < 8; ++kt)
            #pragma unroll
            for (int g = 0; g < 4; ++g)
                acc[g] = __builtin_amdgcn_mfma_f32_16x16x32_f16(a[kt], bf[g][kt], acc[g], 0, 0, 0);
        f16 ov[16];
        #pragma unroll
        for (int g = 0; g < 4; ++g)
            #pragma unroll
            for (int r = 0; r < 4; ++r) ov[g * 4 + r] = (f16)acc[g][r];
        f16* dst = xgc + (((size_t)(s * 16 + bg) * 16) + ns * 4 + wv) * 1024 + l * 16;
        *(uint4*)dst = *(uint4*)&ov[0];
        *((uint4*)dst + 1) = *(uint4*)&ov[8];
    }
}

// ---------------- final projection (chunk) ----------------
// grid: 16(bg) x (tc/4). block 4 waves; wave wv handles local step s = tb*4+wv.
__launch_bounds__(256, 1)
__global__ void fc_out(const f16* __restrict__ h2c, const f16* __restrict__ Wfcp,
                       const float* __restrict__ bfc, float* __restrict__ out, int t0) {
    const int tid = threadIdx.x, wv = tid >> 6, l = tid & 63, l15 = l & 15, lq = l >> 4;
    const int bid = blockIdx.x, bg = bid & 15, tb = bid >> 4;
    const int s = tb * 4 + wv;

    f16x8 bf[6][8];
    #pragma unroll
    for (int nt = 0; nt < 6; ++nt)
        #pragma unroll
        for (int kt = 0; kt < 8; ++kt)
            bf[nt][kt] = *(const f16x8*)&Wfcp[((size_t)(nt * 8 + kt) * 64 + l) * 8];
    float bb[6];
    #pragma unroll
    for (int nt = 0; nt < 6; ++nt) {
        int n = nt * 16 + l15;
        bb[nt] = (n < NV) ? bfc[n] : 0.f;
    }
    const int hswz = 32 * (l15 & 7);

    const f16* blob = h2c + ((size_t)(s * 16 + bg) << 12);
    f16x8 a[8];
    #pragma unroll
    for (int kt = 0; kt < 8; ++kt)
        a[kt] = *(const f16x8*)&blob[l15 * 256 + ((kt * 32 + lq * 8) ^ hswz)];
    f32x4 acc[6];
    #pragma unroll
    for (int nt = 0; nt < 6; ++nt) acc[nt] = (f32x4){bb[nt], bb[nt], bb[nt], bb[nt]};
    #pragma unroll
    for (int kt = 0; kt < 8; ++kt)
        #pragma unroll
        for (int nt = 0; nt < 6; ++nt)
            acc[nt] = __builtin_amdgcn_mfma_f32_16x16x32_f16(a[kt], bf[nt][kt], acc[nt], 0, 0, 0);
    #pragma unroll
    for (int nt = 0; nt < 6; ++nt) {
        int n = nt * 16 + l15;
        if (n < NV) {
            #pragma unroll
            for (int r = 0; r < 4; ++r)
                out[((size_t)(bg * 16 + lq * 4 + r) * NS + (t0 + s)) * NV + n] = acc[nt][r];
        }
    }
}

extern "C" void kernel_launch(void* const* d_in, const int* in_sizes, int n_in,
                              void* d_out, int out_size, void* d_ws, size_t ws_size,
                              hipStream_t stream) {
    const int*   x    = (const int*)  d_in[0];
    const float* emb  = (const float*)d_in[1];
    const float* wih0 = (const float*)d_in[2];
    const float* whh0 = (const float*)d_in[3];
    const float* bih0 = (const float*)d_in[4];
    const float* bhh0 = (const float*)d_in[5];
    const float* wih1 = (const float*)d_in[6];
    const float* whh1 = (const float*)d_in[7];
    const float* bih1 = (const float*)d_in[8];
    const float* bhh1 = (const float*)d_in[9];
    const float* wfc  = (const float*)d_in[10];
    const float* bfc  = (const float*)d_in[11];
    float* out = (float*)d_out;

    char* ws = (char*)d_ws;
    // fixed region (bytes)
    f16*   Wp0  = (f16*)(ws + 0);             //  524288
    f16*   Wp1  = (f16*)(ws + 524288);        //  524288
    f16*   Wxp  = (f16*)(ws + 1048576);       //  524288
    f16*   Wfcp = (f16*)(ws + 1572864);       //   49152
    f16*   T0p  = (f16*)(ws + 1622016);       //  184320
    float* cst0 = (float*)(ws + 1806336);     //  262144
    float* cst1 = (float*)(ws + 2068480);     //  262144
    f16*   hst0 = (f16*)(ws + 2330624);       //  131072
    f16*   hst1 = (f16*)(ws + 2461696);       //  131072
    const size_t base = 2592768;

    // pick chunk length by available workspace: need base + TC*(128K + 512K + 128K)
    int TC = 64;
    if (ws_size >= base + (size_t)256 * 786432 + (1u << 20)) TC = 256;
    else if (ws_size >= base + (size_t)128 * 786432 + (1u << 20)) TC = 128;

    f16* h1c = (f16*)(ws + base);
    f16* xgc = (f16*)(ws + base + (size_t)TC * 131072);
    f16* h2c = (f16*)(ws + base + (size_t)TC * 131072 + (size_t)TC * 524288);

    hipFuncSetAttribute(reinterpret_cast<const void*>(rnn_chunk<0>),
                        hipFuncAttributeMaxDynamicSharedMemorySize, R_LDS_BYTES);
    hipFuncSetAttribute(reinterpret_cast<const void*>(rnn_chunk<1>),
                        hipFuncAttributeMaxDynamicSharedMemorySize, R_LDS_BYTES);

    build_t0p<<<90, 256, 0, stream>>>(emb, wih0, bih0, bhh0, T0p);
    pack_rw<<<128, 256, 0, stream>>>(whh0, Wp0);
    pack_rw<<<128, 256, 0, stream>>>(whh1, Wp1);
    pack_rw<<<128, 256, 0, stream>>>(wih1, Wxp);
    pack_fc<<<12, 256, 0, stream>>>(wfc, Wfcp);

    for (int t0 = 0; t0 < NS; t0 += TC) {
        rnn_chunk<0><<<16, 256, R_LDS_BYTES, stream>>>(Wp0, x, T0p, nullptr,
                                                       h1c, cst0, hst0, t0, TC);
        xg1_gemm<<<16 * 4 * (TC / 16), 256, 0, stream>>>(h1c, Wxp, bih1, bhh1, xgc);
        rnn_chunk<1><<<16, 256, R_LDS_BYTES, stream>>>(Wp1, nullptr, nullptr, xgc,
                                                       h2c, cst1, hst1, t0, TC);
        fc_out<<<16 * (TC / 4), 256, 0, stream>>>(h2c, Wfcp, bfc, out, t0);
    }
}

// Round 6
// 2683.413 us; speedup vs baseline: 2.4079x; 2.4079x over previous
//
#include <hip/hip_runtime.h>
#include <math.h>

typedef _Float16 f16;
typedef _Float16 f16x8 __attribute__((ext_vector_type(8)));
typedef _Float16 f16x4 __attribute__((ext_vector_type(4)));
typedef float f32x4 __attribute__((ext_vector_type(4)));

#define NS     512
#define NG     1024
#define NV     90
#define TC     64

// LDS map for fused_rnn (bytes):
//   [0, 16384)       : h double buffer, 2 x 16 rows x 256 f16 (XOR-swizzled, 32-granule)
//   [16384, 155648)  : per-wave LDS weight frags: wave w at 16384 + w*34816 (34 frags x 1KB)
#define R_LDS_BYTES 155648

// raw v_exp_f32 (no libm range guard; gate pre-activations are bounded)
__device__ __forceinline__ float sgf(float x) {
    return __builtin_amdgcn_rcpf(1.f + __builtin_amdgcn_exp2f(-1.44269504089f * x));
}
__device__ __forceinline__ float thf(float x) {
    return 2.f * __builtin_amdgcn_rcpf(1.f + __builtin_amdgcn_exp2f(-2.88539008178f * x)) - 1.f;
}

// Weight fragment storage classes, f = q*8 + kt, q = jt*4+g (0..15), kt 0..7:
//   kt 0..3            -> AGPR  w_a[q*4+kt]   (64 frags, 256 AGPRs)
//   kt 4               -> ARCH  w_v[q]        (16 frags)
//   kt 5, q < 14       -> ARCH  w_v[16+q]     (14 frags)   [30 arch = 120 VGPRs]
//   kt 5, q >= 14      -> LDS   idx 32+(q-14) (2 frags)
//   kt 6,7             -> LDS   idx q*2+(kt-6)(32 frags)   [34 LDS = 34KB/wave]

// ---------------- setup kernels ----------------

// T0p[v][w][jt][l15][g] f16 = sum_e emb[v][e]*Wih0[n][e] + bih0[n]+bhh0[n],
// n = g*256 + w*64 + jt*16 + l15
__global__ void build_t0p(const float* __restrict__ emb, const float* __restrict__ wih0,
                          const float* __restrict__ bih0, const float* __restrict__ bhh0,
                          f16* __restrict__ t0p) {
    int v = blockIdx.x, tid = threadIdx.x;
    int w = tid >> 6, jt = (tid >> 4) & 3, l15 = tid & 15;
    __shared__ float e[8];
    if (tid < 8) e[tid] = emb[v * 8 + tid];
    __syncthreads();
    f16x4 o;
    #pragma unroll
    for (int g = 0; g < 4; ++g) {
        int n = g * 256 + w * 64 + jt * 16 + l15;
        float s = bih0[n] + bhh0[n];
        #pragma unroll
        for (int k = 0; k < 8; ++k) s += e[k] * wih0[n * 8 + k];
        o[g] = (f16)s;
    }
    *(f16x4*)&t0p[((((size_t)v * 4 + w) * 4 + jt) * 16 + l15) * 4] = o;
}

// pack 1024x256 f32 weight into B-frag layout Wp[(w*128+f)*64+l][8]
__global__ void pack_rw(const float* __restrict__ W, f16* __restrict__ Wp) {
    int gid = blockIdx.x * 256 + threadIdx.x;   // 32768
    int l = gid & 63, f = (gid >> 6) & 127, w = gid >> 13;
    int kt = f & 7, g = (f >> 3) & 3, jt = f >> 5;
    int n = g * 256 + w * 64 + jt * 16 + (l & 15);
    int k = kt * 32 + (l >> 4) * 8;
    f16x8 v;
    #pragma unroll
    for (int e = 0; e < 8; ++e) v[e] = (f16)W[n * 256 + k + e];
    *(f16x8*)&Wp[(size_t)gid * 8] = v;
}

// pack Wfc (90x256) zero-padded to 96 rows: Wfcp[(nt*8+kt)*64+l][8]
__global__ void pack_fc(const float* __restrict__ Wfc, f16* __restrict__ Wp) {
    int gid = blockIdx.x * 256 + threadIdx.x;   // 3072
    int l = gid & 63, kt = (gid >> 6) & 7, nt = gid >> 9;
    int n = nt * 16 + (l & 15);
    int k = kt * 32 + (l >> 4) * 8;
    f16x8 v;
    #pragma unroll
    for (int e = 0; e < 8; ++e) v[e] = (n < NV) ? (f16)Wfc[n * 256 + k + e] : (f16)0.f;
    *(f16x8*)&Wp[(size_t)gid * 8] = v;
}

// ---------------- recurrent chunk body (both layers) ----------------
template<int LAYER>
__device__ __forceinline__ void rnn_body(const f16* __restrict__ Wp, const int* __restrict__ x,
                                         const f16* __restrict__ T0p, const f16* __restrict__ xgc,
                                         f16* __restrict__ hdump, float* __restrict__ cst,
                                         f16* __restrict__ hst, int t0, int bg, char* smem) {
    f16* hb = (f16*)smem;   // 2 x 4096 f16
    const int tid = threadIdx.x;
    const int w = tid >> 6, l = tid & 63, l15 = l & 15, lq = l >> 4;

    const f16* wgl = Wp + ((size_t)w * 128) * 512 + l * 8;   // frag f at +f*512 (f16)
    f16* wlds = (f16*)(smem + 16384 + w * 34816);

    // stage LDS-resident frags (34/wave)
    #pragma unroll
    for (int fi = 0; fi < 34; ++fi) {
        int f = (fi < 32) ? ((fi >> 1) * 8 + 6 + (fi & 1)) : ((14 + (fi - 32)) * 8 + 5);
        *(f16x8*)&wlds[fi * 512 + l * 8] = *(const f16x8*)&wgl[(size_t)f * 512];
    }

    // AGPR-resident frags: pinned with "a" constraint; MFMA consumes AGPR B-operand
    // directly on gfx950 (unified file) - no accvgpr_read round-trips.
    f32x4 w_a[64];
    #pragma unroll
    for (int q = 0; q < 16; ++q)
        #pragma unroll
        for (int kt = 0; kt < 4; ++kt)
            w_a[q * 4 + kt] = *(const f32x4*)&wgl[(size_t)(q * 8 + kt) * 512];
    #pragma unroll
    for (int i = 0; i < 64; ++i) asm volatile("" : "+a"(w_a[i]));

    // arch-VGPR-resident frags (30)
    f32x4 w_v[30];
    #pragma unroll
    for (int q = 0; q < 16; ++q) w_v[q] = *(const f32x4*)&wgl[(size_t)(q * 8 + 4) * 512];
    #pragma unroll
    for (int q = 0; q < 14; ++q) w_v[16 + q] = *(const f32x4*)&wgl[(size_t)(q * 8 + 5) * 512];
    #pragma unroll
    for (int i = 0; i < 30; ++i) asm volatile("" : "+v"(w_v[i]));

    float c[16];
    if (t0 == 0) {
        #pragma unroll
        for (int i = 0; i < 16; ++i) hb[i * 256 + tid] = (f16)0.f;
        #pragma unroll
        for (int i = 0; i < 16; ++i) c[i] = 0.f;
    } else {
        const char* hsrc = (const char*)hst + (size_t)bg * 8192 + tid * 32;
        *(uint4*)(smem + tid * 32)      = *(const uint4*)hsrc;
        *(uint4*)(smem + tid * 32 + 16) = *(const uint4*)(hsrc + 16);
        const float* cp = cst + (((size_t)bg * 4 + w) * 64 + l) * 16;
        #pragma unroll
        for (int i = 0; i < 16; ++i) c[i] = cp[i];
    }
    __syncthreads();

    const int hswz = 32 * (l15 & 7);

    for (int s = 0; s < TC; ++s) {
        const int t = t0 + s;
        const int rb = (s & 1) * 4096, wb = rb ^ 4096;

        // dump h(t-1) (raw swizzled blob) - fire and forget
        if (s > 0) {
            const char* src = smem + rb * 2 + tid * 32;
            uint4 d0 = *(const uint4*)src;
            uint4 d1 = *(const uint4*)(src + 16);
            f16* dst = hdump + (((size_t)(s - 1) * 16 + bg) << 12) + tid * 16;
            *(uint4*)dst = d0;
            *((uint4*)dst + 1) = d1;
        }

        int xv[4];
        if constexpr (LAYER == 0) {
            #pragma unroll
            for (int r = 0; r < 4; ++r)
                xv[r] = x[(bg * 16 + lq * 4 + r) * NS + t];
        }

        uint4 ivq[2][2];
        f16x4 iv0[2][4];
        if constexpr (LAYER == 0) {
            #pragma unroll
            for (int r = 0; r < 4; ++r)
                iv0[0][r] = *(const f16x4*)&T0p[((((size_t)xv[r] * 4 + w) * 4 + 0) * 16 + l15) * 4];
        } else {
            const f16* p_ = xgc + (((size_t)(s * 16 + bg) * 16) + w * 4 + 0) * 1024 + l * 16;
            ivq[0][0] = *(const uint4*)p_;
            ivq[0][1] = *(const uint4*)(p_ + 8);
        }

        // A-fragments of h(t-1): load once per step
        f16x8 a[8];
        #pragma unroll
        for (int kt = 0; kt < 8; ++kt)
            a[kt] = *(const f16x8*)&hb[rb + l15 * 256 + ((kt * 32 + lq * 8) ^ hswz)];

        #pragma unroll
        for (int jt = 0; jt < 4; ++jt) {
            const int cs = jt & 1, nx = cs ^ 1;
            if (jt < 3) {
                if constexpr (LAYER == 0) {
                    #pragma unroll
                    for (int r = 0; r < 4; ++r)
                        iv0[nx][r] = *(const f16x4*)&T0p[((((size_t)xv[r] * 4 + w) * 4 + (jt + 1)) * 16 + l15) * 4];
                } else {
                    const f16* p_ = xgc + (((size_t)(s * 16 + bg) * 16) + w * 4 + (jt + 1)) * 1024 + l * 16;
                    ivq[nx][0] = *(const uint4*)p_;
                    ivq[nx][1] = *(const uint4*)(p_ + 8);
                }
            }

            f32x4 acc[4];
            #pragma unroll
            for (int g = 0; g < 4; ++g) acc[g] = (f32x4){0.f, 0.f, 0.f, 0.f};

            #pragma unroll
            for (int kt = 0; kt < 8; ++kt) {
                #pragma unroll
                for (int g = 0; g < 4; ++g) {
                    const int q = jt * 4 + g;
                    f16x8 bfr;
                    if (kt < 4)                 bfr = __builtin_bit_cast(f16x8, w_a[q * 4 + kt]);
                    else if (kt == 4)           bfr = __builtin_bit_cast(f16x8, w_v[q]);
                    else if (kt == 5 && q < 14) bfr = __builtin_bit_cast(f16x8, w_v[16 + q]);
                    else if (kt == 5)           bfr = *(const f16x8*)&wlds[(32 + (q - 14)) * 512 + l * 8];
                    else                        bfr = *(const f16x8*)&wlds[(q * 2 + (kt - 6)) * 512 + l * 8];
                    acc[g] = __builtin_amdgcn_mfma_f32_16x16x32_f16(a[kt], bfr, acc[g], 0, 0, 0);
                }
            }

            const f16* ivf = (const f16*)&ivq[cs][0];
            #pragma unroll
            for (int r = 0; r < 4; ++r) {
                float gi, gf, gg, go;
                if constexpr (LAYER == 0) {
                    gi = acc[0][r] + (float)iv0[cs][r][0];
                    gf = acc[1][r] + (float)iv0[cs][r][1];
                    gg = acc[2][r] + (float)iv0[cs][r][2];
                    go = acc[3][r] + (float)iv0[cs][r][3];
                } else {
                    gi = acc[0][r] + (float)ivf[0 * 4 + r];
                    gf = acc[1][r] + (float)ivf[1 * 4 + r];
                    gg = acc[2][r] + (float)ivf[2 * 4 + r];
                    go = acc[3][r] + (float)ivf[3 * 4 + r];
                }
                float si = sgf(gi), sf = sgf(gf), tg = thf(gg), so = sgf(go);
                const int ci = jt * 4 + r;
                c[ci] = sf * c[ci] + si * tg;
                float h = so * thf(c[ci]);
                const int b = lq * 4 + r;
                hb[wb + b * 256 + ((w * 64 + jt * 16 + l15) ^ (32 * (b & 7)))] = (f16)h;
            }
        }
        __syncthreads();
    }
    // epilogue: final h lives in buffer 0 (TC even). dump it + save state.
    {
        const char* src = smem + tid * 32;
        uint4 d0 = *(const uint4*)src;
        uint4 d1 = *(const uint4*)(src + 16);
        f16* dst = hdump + (((size_t)(TC - 1) * 16 + bg) << 12) + tid * 16;
        *(uint4*)dst = d0;
        *((uint4*)dst + 1) = d1;
        char* hdst = (char*)hst + (size_t)bg * 8192 + tid * 32;
        *(uint4*)hdst = d0;
        *(uint4*)(hdst + 16) = d1;
        float* cp = cst + (((size_t)bg * 4 + w) * 64 + l) * 16;
        #pragma unroll
        for (int i = 0; i < 16; ++i) cp[i] = c[i];
    }
}

// Co-launched: blocks 0-15 run layer0 chunk k (steps t0l0..), blocks 16-31 run
// layer1 chunk k-1 (steps t0l0-TC..). Independent work -> 32 CUs busy.
__global__ __launch_bounds__(256, 1)
void fused_rnn(const f16* __restrict__ Wp0, const f16* __restrict__ Wp1,
               const int* __restrict__ x, const f16* __restrict__ T0p,
               const f16* __restrict__ xgc, f16* __restrict__ h1c, f16* __restrict__ h2c,
               float* __restrict__ cst0, float* __restrict__ cst1,
               f16* __restrict__ hst0, f16* __restrict__ hst1,
               int t0l0, int do0, int do1) {
    extern __shared__ char smem[];
    if (blockIdx.x < 16) {
        if (do0) rnn_body<0>(Wp0, x, T0p, nullptr, h1c, cst0, hst0, t0l0, blockIdx.x, smem);
    } else {
        if (do1) rnn_body<1>(Wp1, nullptr, nullptr, xgc, h2c, cst1, hst1, t0l0 - TC, blockIdx.x - 16, smem);
    }
}

// ---------------- xg1 = Wih1 @ h1 + (bih1+bhh1), frag-layout output (chunk) -----
// grid: 16(bg) x 4(ns) x (TC/16). block 256: wave wv owns jt=wv.
__launch_bounds__(256, 1)
__global__ void xg1_gemm(const f16* __restrict__ h1c, const f16* __restrict__ Wxp,
                         const float* __restrict__ bih1, const float* __restrict__ bhh1,
                         f16* __restrict__ xgc) {
    const int tid = threadIdx.x, wv = tid >> 6, l = tid & 63, l15 = l & 15, lq = l >> 4;
    const int bid = blockIdx.x, bg = bid & 15, ns = (bid >> 4) & 3, tcc = bid >> 6;

    f16x8 bf[4][8];
    #pragma unroll
    for (int g = 0; g < 4; ++g)
        #pragma unroll
        for (int kt = 0; kt < 8; ++kt)
            bf[g][kt] = *(const f16x8*)&Wxp[((size_t)(ns * 128 + (wv * 4 + g) * 8 + kt) * 64 + l) * 8];
    float bs[4];
    #pragma unroll
    for (int g = 0; g < 4; ++g) {
        int n = g * 256 + ns * 64 + wv * 16 + l15;
        bs[g] = bih1[n] + bhh1[n];
    }
    const int hswz = 32 * (l15 & 7);

    for (int tt = 0; tt < 16; ++tt) {
        int s = tcc * 16 + tt;
        const f16* blob = h1c + ((size_t)(s * 16 + bg) << 12);
        f16x8 a[8];
        #pragma unroll
        for (int kt = 0; kt < 8; ++kt)
            a[kt] = *(const f16x8*)&blob[l15 * 256 + ((kt * 32 + lq * 8) ^ hswz)];
        f32x4 acc[4];
        #pragma unroll
        for (int g = 0; g < 4; ++g) acc[g] = (f32x4){bs[g], bs[g], bs[g], bs[g]};
        #pragma unroll
        for (int kt = 0; kt < 8; ++kt)
            #pragma unroll
            for (int g = 0; g < 4; ++g)
                acc[g] = __builtin_amdgcn_mfma_f32_16x16x32_f16(a[kt], bf[g][kt], acc[g], 0, 0, 0);
        f16 ov[16];
        #pragma unroll
        for (int g = 0; g < 4; ++g)
            #pragma unroll
            for (int r = 0; r < 4; ++r) ov[g * 4 + r] = (f16)acc[g][r];
        f16* dst = xgc + (((size_t)(s * 16 + bg) * 16) + ns * 4 + wv) * 1024 + l * 16;
        *(uint4*)dst = *(uint4*)&ov[0];
        *((uint4*)dst + 1) = *(uint4*)&ov[8];
    }
}

// ---------------- final projection (chunk) ----------------
// grid: 16(bg) x (TC/4). block 4 waves; wave wv handles local step s = tb*4+wv.
__launch_bounds__(256, 1)
__global__ void fc_out(const f16* __restrict__ h2c, const f16* __restrict__ Wfcp,
                       const float* __restrict__ bfc, float* __restrict__ out, int t0) {
    const int tid = threadIdx.x, wv = tid >> 6, l = tid & 63, l15 = l & 15, lq = l >> 4;
    const int bid = blockIdx.x, bg = bid & 15, tb = bid >> 4;
    const int s = tb * 4 + wv;

    f16x8 bf[6][8];
    #pragma unroll
    for (int nt = 0; nt < 6; ++nt)
        #pragma unroll
        for (int kt = 0; kt < 8; ++kt)
            bf[nt][kt] = *(const f16x8*)&Wfcp[((size_t)(nt * 8 + kt) * 64 + l) * 8];
    float bb[6];
    #pragma unroll
    for (int nt = 0; nt < 6; ++nt) {
        int n = nt * 16 + l15;
        bb[nt] = (n < NV) ? bfc[n] : 0.f;
    }
    const int hswz = 32 * (l15 & 7);

    const f16* blob = h2c + ((size_t)(s * 16 + bg) << 12);
    f16x8 a[8];
    #pragma unroll
    for (int kt = 0; kt < 8; ++kt)
        a[kt] = *(const f16x8*)&blob[l15 * 256 + ((kt * 32 + lq * 8) ^ hswz)];
    f32x4 acc[6];
    #pragma unroll
    for (int nt = 0; nt < 6; ++nt) acc[nt] = (f32x4){bb[nt], bb[nt], bb[nt], bb[nt]};
    #pragma unroll
    for (int kt = 0; kt < 8; ++kt)
        #pragma unroll
        for (int nt = 0; nt < 6; ++nt)
            acc[nt] = __builtin_amdgcn_mfma_f32_16x16x32_f16(a[kt], bf[nt][kt], acc[nt], 0, 0, 0);
    #pragma unroll
    for (int nt = 0; nt < 6; ++nt) {
        int n = nt * 16 + l15;
        if (n < NV) {
            #pragma unroll
            for (int r = 0; r < 4; ++r)
                out[((size_t)(bg * 16 + lq * 4 + r) * NS + (t0 + s)) * NV + n] = acc[nt][r];
        }
    }
}

extern "C" void kernel_launch(void* const* d_in, const int* in_sizes, int n_in,
                              void* d_out, int out_size, void* d_ws, size_t ws_size,
                              hipStream_t stream) {
    const int*   x    = (const int*)  d_in[0];
    const float* emb  = (const float*)d_in[1];
    const float* wih0 = (const float*)d_in[2];
    const float* whh0 = (const float*)d_in[3];
    const float* bih0 = (const float*)d_in[4];
    const float* bhh0 = (const float*)d_in[5];
    const float* wih1 = (const float*)d_in[6];
    const float* whh1 = (const float*)d_in[7];
    const float* bih1 = (const float*)d_in[8];
    const float* bhh1 = (const float*)d_in[9];
    const float* wfc  = (const float*)d_in[10];
    const float* bfc  = (const float*)d_in[11];
    float* out = (float*)d_out;

    char* ws = (char*)d_ws;
    // fixed region (bytes)
    f16*   Wp0  = (f16*)(ws + 0);             //  524288
    f16*   Wp1  = (f16*)(ws + 524288);        //  524288
    f16*   Wxp  = (f16*)(ws + 1048576);       //  524288
    f16*   Wfcp = (f16*)(ws + 1572864);       //   49152
    f16*   T0p  = (f16*)(ws + 1622016);       //  184320
    float* cst0 = (float*)(ws + 1806336);     //  262144
    float* cst1 = (float*)(ws + 2068480);     //  262144
    f16*   hst0 = (f16*)(ws + 2330624);       //  131072
    f16*   hst1 = (f16*)(ws + 2461696);       //  131072
    const size_t base = 2592768;

    // chunk buffers at TC=64: h1c 8.39MB, xgc 33.5MB, h2c 8.39MB  (~53MB total;
    // R3 proved ws >= ~204MB since TC=256 path was taken there)
    f16* h1c = (f16*)(ws + base);
    f16* xgc = (f16*)(ws + base + (size_t)TC * 131072);
    f16* h2c = (f16*)(ws + base + (size_t)TC * 131072 + (size_t)TC * 524288);

    hipFuncSetAttribute(reinterpret_cast<const void*>(fused_rnn),
                        hipFuncAttributeMaxDynamicSharedMemorySize, R_LDS_BYTES);

    build_t0p<<<90, 256, 0, stream>>>(emb, wih0, bih0, bhh0, T0p);
    pack_rw<<<128, 256, 0, stream>>>(whh0, Wp0);
    pack_rw<<<128, 256, 0, stream>>>(whh1, Wp1);
    pack_rw<<<128, 256, 0, stream>>>(wih1, Wxp);
    pack_fc<<<12, 256, 0, stream>>>(wfc, Wfcp);

    const int NCH = NS / TC;   // 8
    for (int k = 0; k <= NCH; ++k) {
        fused_rnn<<<32, 256, R_LDS_BYTES, stream>>>(Wp0, Wp1, x, T0p, xgc, h1c, h2c,
                                                    cst0, cst1, hst0, hst1,
                                                    k * TC, (int)(k < NCH), (int)(k > 0));
        if (k < NCH) xg1_gemm<<<16 * 4 * (TC / 16), 256, 0, stream>>>(h1c, Wxp, bih1, bhh1, xgc);
        if (k > 0)   fc_out<<<16 * (TC / 4), 256, 0, stream>>>(h2c, Wfcp, bfc, out, (k - 1) * TC);
    }
}

// Round 7
// 1977.594 us; speedup vs baseline: 3.2673x; 1.3569x over previous
//
#include <hip/hip_runtime.h>
#include <math.h>

typedef _Float16 f16;
typedef _Float16 f16x8 __attribute__((ext_vector_type(8)));
typedef _Float16 f16x4 __attribute__((ext_vector_type(4)));
typedef float f32x4 __attribute__((ext_vector_type(4)));

#define NS     512
#define NG     1024
#define NV     90
#define TC     64

// LDS map for fused_rnn (bytes):
//   [0, 16384)       : h double buffer, 2 x 16 rows x 256 f16 (64B-granule XOR swizzle,
//                      rows 2-15 permanently zero at M=2)
//   [16384, 155648)  : per-wave LDS weight frags: wave w at 16384 + w*34816 (34 frags x 1KB)
#define R_LDS_BYTES 155648

__device__ __forceinline__ float sgf(float x) {
    return __builtin_amdgcn_rcpf(1.f + __builtin_amdgcn_exp2f(-1.44269504089f * x));
}
__device__ __forceinline__ float thf(float x) {
    return 2.f * __builtin_amdgcn_rcpf(1.f + __builtin_amdgcn_exp2f(-2.88539008178f * x)) - 1.f;
}

// Weight fragment storage classes, f = q*8 + kt, q = jt*4+g (0..15), kt 0..7:
//   kt 0..3            -> AGPR  w_a[q*4+kt]   (64 frags, 256 AGPRs)
//   kt 4               -> ARCH  w_v[q]        (16 frags)
//   kt 5, q < 14       -> ARCH  w_v[16+q]     (14 frags)
//   kt 5, q >= 14      -> LDS   idx 32+(q-14) (2 frags)
//   kt 6,7             -> LDS   idx q*2+(kt-6)(32 frags)

// ---------------- setup kernels ----------------

// T0p[v][hid][g] f16 (gate-interleaved): = sum_e emb[v][e]*Wih0[n][e] + bih0[n]+bhh0[n],
// n = g*256 + hid
__global__ void build_t0p(const float* __restrict__ emb, const float* __restrict__ wih0,
                          const float* __restrict__ bih0, const float* __restrict__ bhh0,
                          f16* __restrict__ t0p) {
    int v = blockIdx.x, hid = threadIdx.x;
    __shared__ float e[8];
    if (hid < 8) e[hid] = emb[v * 8 + hid];
    __syncthreads();
    f16x4 o;
    #pragma unroll
    for (int g = 0; g < 4; ++g) {
        int n = g * 256 + hid;
        float s = bih0[n] + bhh0[n];
        #pragma unroll
        for (int k = 0; k < 8; ++k) s += e[k] * wih0[n * 8 + k];
        o[g] = (f16)s;
    }
    *(f16x4*)&t0p[((size_t)v * 256 + hid) * 4] = o;
}

// pack 1024x256 f32 weight into B-frag layout Wp[(w*128+f)*64+l][8]
__global__ void pack_rw(const float* __restrict__ W, f16* __restrict__ Wp) {
    int gid = blockIdx.x * 256 + threadIdx.x;   // 32768
    int l = gid & 63, f = (gid >> 6) & 127, w = gid >> 13;
    int kt = f & 7, g = (f >> 3) & 3, jt = f >> 5;
    int n = g * 256 + w * 64 + jt * 16 + (l & 15);
    int k = kt * 32 + (l >> 4) * 8;
    f16x8 v;
    #pragma unroll
    for (int e = 0; e < 8; ++e) v[e] = (f16)W[n * 256 + k + e];
    *(f16x8*)&Wp[(size_t)gid * 8] = v;
}

// pack Wfc (90x256) zero-padded to 96 rows: Wfcp[(nt*8+kt)*64+l][8]
__global__ void pack_fc(const float* __restrict__ Wfc, f16* __restrict__ Wp) {
    int gid = blockIdx.x * 256 + threadIdx.x;   // 3072
    int l = gid & 63, kt = (gid >> 6) & 7, nt = gid >> 9;
    int n = nt * 16 + (l & 15);
    int k = kt * 32 + (l >> 4) * 8;
    f16x8 v;
    #pragma unroll
    for (int e = 0; e < 8; ++e) v[e] = (n < NV) ? (f16)Wfc[n * 256 + k + e] : (f16)0.f;
    *(f16x8*)&Wp[(size_t)gid * 8] = v;
}

// ---------------- recurrent chunk body, M=2 rows per block ----------------
// 128 blocks per layer (bp = 0..127 -> rows 2bp, 2bp+1), 4 waves, 1/SIMD.
// Wave w owns hidden slice [w*64, w*64+64). Weight residency identical to R6.
// hb rows 2-15 stay zero -> MFMA acc rows 2-3.. garbage-free; EW on lq==0 lanes only.
// h(t) dumped every step to hdump[s][row][256] (plain layout).
template<int LAYER>
__device__ __forceinline__ void rnn_body(const f16* __restrict__ Wp, const int* __restrict__ x,
                                         const f16* __restrict__ T0p, const f16* __restrict__ xgc,
                                         f16* __restrict__ hdump, float* __restrict__ cst,
                                         f16* __restrict__ hst, int t0, int bp, char* smem) {
    f16* hb = (f16*)smem;   // 2 x 4096 f16
    const int tid = threadIdx.x;
    const int w = tid >> 6, l = tid & 63, l15 = l & 15, lq = l >> 4;
    const int R0 = bp * 2;

    const f16* wgl = Wp + ((size_t)w * 128) * 512 + l * 8;   // frag f at +f*512 (f16)
    f16* wlds = (f16*)(smem + 16384 + w * 34816);

    // stage LDS-resident frags (34/wave; wave-local, no barrier needed)
    #pragma unroll
    for (int fi = 0; fi < 34; ++fi) {
        int f = (fi < 32) ? ((fi >> 1) * 8 + 6 + (fi & 1)) : ((14 + (fi - 32)) * 8 + 5);
        *(f16x8*)&wlds[fi * 512 + l * 8] = *(const f16x8*)&wgl[(size_t)f * 512];
    }

    // AGPR-resident frags (pinned)
    f32x4 w_a[64];
    #pragma unroll
    for (int q = 0; q < 16; ++q)
        #pragma unroll
        for (int kt = 0; kt < 4; ++kt)
            w_a[q * 4 + kt] = *(const f32x4*)&wgl[(size_t)(q * 8 + kt) * 512];
    #pragma unroll
    for (int i = 0; i < 64; ++i) asm volatile("" : "+a"(w_a[i]));

    // arch-VGPR-resident frags (30, pinned)
    f32x4 w_v[30];
    #pragma unroll
    for (int q = 0; q < 16; ++q) w_v[q] = *(const f32x4*)&wgl[(size_t)(q * 8 + 4) * 512];
    #pragma unroll
    for (int q = 0; q < 14; ++q) w_v[16 + q] = *(const f32x4*)&wgl[(size_t)(q * 8 + 5) * 512];
    #pragma unroll
    for (int i = 0; i < 30; ++i) asm volatile("" : "+v"(w_v[i]));

    // zero all of hb (both buffers; rows 2-15 stay zero forever)
    #pragma unroll
    for (int i = 0; i < 4; ++i) *(uint4*)(smem + tid * 64 + i * 16) = (uint4){0, 0, 0, 0};
    __syncthreads();

    float c[8];
    #pragma unroll
    for (int i = 0; i < 8; ++i) c[i] = 0.f;
    if (t0 > 0) {
        // restore h rows 0,1 (swizzled) + c
        #pragma unroll
        for (int i = 0; i < 2; ++i) {
            int idx = tid + i * 256;
            int r = idx >> 8, hid = idx & 255;
            hb[r * 256 + (hid ^ (32 * r))] = hst[(size_t)bp * 512 + r * 256 + hid];
        }
        if (lq == 0) {
            const float* cp = cst + (((size_t)bp * 4 + w) * 16 + l15) * 8;
            #pragma unroll
            for (int i = 0; i < 8; ++i) c[i] = cp[i];
        }
    }
    __syncthreads();

    // iv prologue: (s=0, jt=0)
    f16x4 ivc0 = {}, ivc1 = {};
    int xv0 = 0, xv1 = 0, xvn0 = 0, xvn1 = 0;
    if (lq == 0) {
        const int hid0 = w * 64 + l15;
        if constexpr (LAYER == 0) {
            xv0 = x[(R0 + 0) * NS + t0];
            xv1 = x[(R0 + 1) * NS + t0];
            ivc0 = *(const f16x4*)&T0p[((size_t)xv0 * 256 + hid0) * 4];
            ivc1 = *(const f16x4*)&T0p[((size_t)xv1 * 256 + hid0) * 4];
        } else {
            ivc0 = *(const f16x4*)&xgc[((size_t)(R0 + 0) * 256 + hid0) * 4];
            ivc1 = *(const f16x4*)&xgc[((size_t)(R0 + 1) * 256 + hid0) * 4];
        }
    }

    for (int s = 0; s < TC; ++s) {
        const int t = t0 + s;
        const int rb = (s & 1) * 4096, wb = rb ^ 4096;

        // A-fragments of h(t-1)
        f16x8 a[8];
        #pragma unroll
        for (int kt = 0; kt < 8; ++kt)
            a[kt] = *(const f16x8*)&hb[rb + l15 * 256 + ((kt * 32 + lq * 8) ^ (32 * (l15 & 7)))];

        // next-step tokens (hidden under MFMA)
        if constexpr (LAYER == 0) {
            if (lq == 0) {
                int tn = (t + 1 < NS) ? t + 1 : NS - 1;
                xvn0 = x[(R0 + 0) * NS + tn];
                xvn1 = x[(R0 + 1) * NS + tn];
            }
        }

        #pragma unroll
        for (int jt = 0; jt < 4; ++jt) {
            // prefetch next iv (jt+1, or next step's jt=0)
            f16x4 ivn0 = {}, ivn1 = {};
            if (lq == 0) {
                if (jt < 3) {
                    const int hidN = w * 64 + (jt + 1) * 16 + l15;
                    if constexpr (LAYER == 0) {
                        ivn0 = *(const f16x4*)&T0p[((size_t)xv0 * 256 + hidN) * 4];
                        ivn1 = *(const f16x4*)&T0p[((size_t)xv1 * 256 + hidN) * 4];
                    } else {
                        ivn0 = *(const f16x4*)&xgc[(((size_t)s * 256 + R0 + 0) * 256 + hidN) * 4];
                        ivn1 = *(const f16x4*)&xgc[(((size_t)s * 256 + R0 + 1) * 256 + hidN) * 4];
                    }
                } else {
                    const int sn = (s + 1 < TC) ? s + 1 : s;
                    const int hid0 = w * 64 + l15;
                    if constexpr (LAYER == 0) {
                        ivn0 = *(const f16x4*)&T0p[((size_t)xvn0 * 256 + hid0) * 4];
                        ivn1 = *(const f16x4*)&T0p[((size_t)xvn1 * 256 + hid0) * 4];
                    } else {
                        ivn0 = *(const f16x4*)&xgc[(((size_t)sn * 256 + R0 + 0) * 256 + hid0) * 4];
                        ivn1 = *(const f16x4*)&xgc[(((size_t)sn * 256 + R0 + 1) * 256 + hid0) * 4];
                    }
                }
            }

            f32x4 acc[4];
            #pragma unroll
            for (int g = 0; g < 4; ++g) acc[g] = (f32x4){0.f, 0.f, 0.f, 0.f};

            #pragma unroll
            for (int kt = 0; kt < 8; ++kt) {
                #pragma unroll
                for (int g = 0; g < 4; ++g) {
                    const int q = jt * 4 + g;
                    f16x8 bfr;
                    if (kt < 4)                 bfr = __builtin_bit_cast(f16x8, w_a[q * 4 + kt]);
                    else if (kt == 4)           bfr = __builtin_bit_cast(f16x8, w_v[q]);
                    else if (kt == 5 && q < 14) bfr = __builtin_bit_cast(f16x8, w_v[16 + q]);
                    else if (kt == 5)           bfr = *(const f16x8*)&wlds[(32 + (q - 14)) * 512 + l * 8];
                    else                        bfr = *(const f16x8*)&wlds[(q * 2 + (kt - 6)) * 512 + l * 8];
                    acc[g] = __builtin_amdgcn_mfma_f32_16x16x32_f16(a[kt], bfr, acc[g], 0, 0, 0);
                }
            }

            // elementwise: 2 rows, lanes lq==0 only
            if (lq == 0) {
                #pragma unroll
                for (int r = 0; r < 2; ++r) {
                    const f16x4 iv = r ? ivc1 : ivc0;
                    float gi = acc[0][r] + (float)iv[0];
                    float gf = acc[1][r] + (float)iv[1];
                    float gg = acc[2][r] + (float)iv[2];
                    float go = acc[3][r] + (float)iv[3];
                    float si = sgf(gi), sf = sgf(gf), tg = thf(gg), so = sgf(go);
                    const int ci = jt * 2 + r;
                    c[ci] = sf * c[ci] + si * tg;
                    float h = so * thf(c[ci]);
                    const int hid = w * 64 + jt * 16 + l15;
                    hb[wb + r * 256 + (hid ^ (32 * r))] = (f16)h;
                    hdump[((size_t)s * 256 + R0 + r) * 256 + hid] = (f16)h;
                }
            }
            ivc0 = ivn0; ivc1 = ivn1;
            if constexpr (LAYER == 0) {
                if (jt == 3) { xv0 = xvn0; xv1 = xvn1; }
            }
        }
        __syncthreads();
    }
    // epilogue: save state (final h in buffer 0 since TC even)
    if (lq == 0) {
        float* cp = cst + (((size_t)bp * 4 + w) * 16 + l15) * 8;
        #pragma unroll
        for (int i = 0; i < 8; ++i) cp[i] = c[i];
    }
    #pragma unroll
    for (int i = 0; i < 2; ++i) {
        int idx = tid + i * 256;
        int r = idx >> 8, hid = idx & 255;
        hst[(size_t)bp * 512 + r * 256 + hid] = hb[r * 256 + (hid ^ (32 * r))];
    }
}

// Co-launched: blocks 0-127 = layer0 chunk k, blocks 128-255 = layer1 chunk k-1.
__global__ __launch_bounds__(256, 1)
void fused_rnn(const f16* __restrict__ Wp0, const f16* __restrict__ Wp1,
               const int* __restrict__ x, const f16* __restrict__ T0p,
               const f16* __restrict__ xgc, f16* __restrict__ h1g, f16* __restrict__ h2g,
               float* __restrict__ cst0, float* __restrict__ cst1,
               f16* __restrict__ hst0, f16* __restrict__ hst1,
               int t0l0, int do0, int do1) {
    extern __shared__ char smem[];
    if (blockIdx.x < 128) {
        if (do0) rnn_body<0>(Wp0, x, T0p, nullptr, h1g, cst0, hst0, t0l0, blockIdx.x, smem);
    } else {
        if (do1) rnn_body<1>(Wp1, nullptr, nullptr, xgc, h2g, cst1, hst1, t0l0 - TC, blockIdx.x - 128, smem);
    }
}

// ---------------- xg1 = Wih1 @ h1 + (bih1+bhh1) -> xgc[s][row][hid][g] f16 -----
// grid: 16(bg) x 4(ns) x (TC/16). block 256: wave wv owns 16-hid subtile.
__launch_bounds__(256, 1)
__global__ void xg1_gemm(const f16* __restrict__ h1g, const f16* __restrict__ Wxp,
                         const float* __restrict__ bih1, const float* __restrict__ bhh1,
                         f16* __restrict__ xgc) {
    const int tid = threadIdx.x, wv = tid >> 6, l = tid & 63, l15 = l & 15, lq = l >> 4;
    const int bid = blockIdx.x, bg = bid & 15, ns = (bid >> 4) & 3, tcc = bid >> 6;

    f16x8 bf[4][8];
    #pragma unroll
    for (int g = 0; g < 4; ++g)
        #pragma unroll
        for (int kt = 0; kt < 8; ++kt)
            bf[g][kt] = *(const f16x8*)&Wxp[((size_t)(ns * 128 + (wv * 4 + g) * 8 + kt) * 64 + l) * 8];
    float bs[4];
    #pragma unroll
    for (int g = 0; g < 4; ++g) {
        int n = g * 256 + ns * 64 + wv * 16 + l15;
        bs[g] = bih1[n] + bhh1[n];
    }
    const int hid = ns * 64 + wv * 16 + l15;

    for (int tt = 0; tt < 16; ++tt) {
        int s = tcc * 16 + tt;
        f16x8 a[8];
        #pragma unroll
        for (int kt = 0; kt < 8; ++kt)
            a[kt] = *(const f16x8*)&h1g[((size_t)s * 256 + bg * 16 + l15) * 256 + kt * 32 + lq * 8];
        f32x4 acc[4];
        #pragma unroll
        for (int g = 0; g < 4; ++g) acc[g] = (f32x4){bs[g], bs[g], bs[g], bs[g]};
        #pragma unroll
        for (int kt = 0; kt < 8; ++kt)
            #pragma unroll
            for (int g = 0; g < 4; ++g)
                acc[g] = __builtin_amdgcn_mfma_f32_16x16x32_f16(a[kt], bf[g][kt], acc[g], 0, 0, 0);
        #pragma unroll
        for (int r = 0; r < 4; ++r) {
            f16x4 o = { (f16)acc[0][r], (f16)acc[1][r], (f16)acc[2][r], (f16)acc[3][r] };
            int row = bg * 16 + lq * 4 + r;
            *(f16x4*)&xgc[(((size_t)s * 256 + row) * 256 + hid) * 4] = o;
        }
    }
}

// ---------------- final projection (chunk) ----------------
// grid: 16(bg) x (TC/4). block 4 waves; wave wv handles local step s = tb*4+wv.
__launch_bounds__(256, 1)
__global__ void fc_out(const f16* __restrict__ h2g, const f16* __restrict__ Wfcp,
                       const float* __restrict__ bfc, float* __restrict__ out, int t0) {
    const int tid = threadIdx.x, wv = tid >> 6, l = tid & 63, l15 = l & 15, lq = l >> 4;
    const int bid = blockIdx.x, bg = bid & 15, tb = bid >> 4;
    const int s = tb * 4 + wv;

    f16x8 bf[6][8];
    #pragma unroll
    for (int nt = 0; nt < 6; ++nt)
        #pragma unroll
        for (int kt = 0; kt < 8; ++kt)
            bf[nt][kt] = *(const f16x8*)&Wfcp[((size_t)(nt * 8 + kt) * 64 + l) * 8];
    float bb[6];
    #pragma unroll
    for (int nt = 0; nt < 6; ++nt) {
        int n = nt * 16 + l15;
        bb[nt] = (n < NV) ? bfc[n] : 0.f;
    }

    f16x8 a[8];
    #pragma unroll
    for (int kt = 0; kt < 8; ++kt)
        a[kt] = *(const f16x8*)&h2g[((size_t)s * 256 + bg * 16 + l15) * 256 + kt * 32 + lq * 8];
    f32x4 acc[6];
    #pragma unroll
    for (int nt = 0; nt < 6; ++nt) acc[nt] = (f32x4){bb[nt], bb[nt], bb[nt], bb[nt]};
    #pragma unroll
    for (int kt = 0; kt < 8; ++kt)
        #pragma unroll
        for (int nt = 0; nt < 6; ++nt)
            acc[nt] = __builtin_amdgcn_mfma_f32_16x16x32_f16(a[kt], bf[nt][kt], acc[nt], 0, 0, 0);
    #pragma unroll
    for (int nt = 0; nt < 6; ++nt) {
        int n = nt * 16 + l15;
        if (n < NV) {
            #pragma unroll
            for (int r = 0; r < 4; ++r)
                out[((size_t)(bg * 16 + lq * 4 + r) * NS + (t0 + s)) * NV + n] = acc[nt][r];
        }
    }
}

extern "C" void kernel_launch(void* const* d_in, const int* in_sizes, int n_in,
                              void* d_out, int out_size, void* d_ws, size_t ws_size,
                              hipStream_t stream) {
    const int*   x    = (const int*)  d_in[0];
    const float* emb  = (const float*)d_in[1];
    const float* wih0 = (const float*)d_in[2];
    const float* whh0 = (const float*)d_in[3];
    const float* bih0 = (const float*)d_in[4];
    const float* bhh0 = (const float*)d_in[5];
    const float* wih1 = (const float*)d_in[6];
    const float* whh1 = (const float*)d_in[7];
    const float* bih1 = (const float*)d_in[8];
    const float* bhh1 = (const float*)d_in[9];
    const float* wfc  = (const float*)d_in[10];
    const float* bfc  = (const float*)d_in[11];
    float* out = (float*)d_out;

    char* ws = (char*)d_ws;
    // fixed region (bytes)
    f16*   Wp0  = (f16*)(ws + 0);             //  524288
    f16*   Wp1  = (f16*)(ws + 524288);        //  524288
    f16*   Wxp  = (f16*)(ws + 1048576);       //  524288
    f16*   Wfcp = (f16*)(ws + 1572864);       //   49152
    f16*   T0p  = (f16*)(ws + 1622016);       //  184320
    float* cst0 = (float*)(ws + 1806336);     //  262144
    float* cst1 = (float*)(ws + 2068480);     //  262144
    f16*   hst0 = (f16*)(ws + 2330624);       //  131072
    f16*   hst1 = (f16*)(ws + 2461696);       //  131072
    const size_t base = 2592768;

    // chunk buffers at TC=64: h1g 8.39MB, xgc 33.5MB, h2g 8.39MB (~53MB; safe)
    f16* h1g = (f16*)(ws + base);
    f16* xgc = (f16*)(ws + base + (size_t)TC * 131072);
    f16* h2g = (f16*)(ws + base + (size_t)TC * 131072 + (size_t)TC * 524288);

    hipFuncSetAttribute(reinterpret_cast<const void*>(fused_rnn),
                        hipFuncAttributeMaxDynamicSharedMemorySize, R_LDS_BYTES);

    build_t0p<<<90, 256, 0, stream>>>(emb, wih0, bih0, bhh0, T0p);
    pack_rw<<<128, 256, 0, stream>>>(whh0, Wp0);
    pack_rw<<<128, 256, 0, stream>>>(whh1, Wp1);
    pack_rw<<<128, 256, 0, stream>>>(wih1, Wxp);
    pack_fc<<<12, 256, 0, stream>>>(wfc, Wfcp);

    const int NCH = NS / TC;   // 8
    for (int k = 0; k <= NCH; ++k) {
        fused_rnn<<<256, 256, R_LDS_BYTES, stream>>>(Wp0, Wp1, x, T0p, xgc, h1g, h2g,
                                                     cst0, cst1, hst0, hst1,
                                                     k * TC, (int)(k < NCH), (int)(k > 0));
        if (k < NCH) xg1_gemm<<<16 * 4 * (TC / 16), 256, 0, stream>>>(h1g, Wxp, bih1, bhh1, xgc);
        if (k > 0)   fc_out<<<16 * (TC / 4), 256, 0, stream>>>(h2g, Wfcp, bfc, out, (k - 1) * TC);
    }
}

// Round 8
// 1885.436 us; speedup vs baseline: 3.4270x; 1.0489x over previous
//
#include <hip/hip_runtime.h>
#include <math.h>

typedef _Float16 f16;
typedef _Float16 f16x8 __attribute__((ext_vector_type(8)));
typedef _Float16 f16x4 __attribute__((ext_vector_type(4)));
typedef float f32x4 __attribute__((ext_vector_type(4)));

#define NS     512
#define NG     1024
#define NV     90
#define TC     64

// LDS map for fused_rnn (bytes):
//   [0, 16384)       : h double buffer, 2 x 16 rows x 256 f16 (64B-granule XOR swizzle)
//   [16384, 155648)  : per-wave LDS weight frags: wave w at 16384 + w*34816 (34 frags x 1KB)
#define R_LDS_BYTES 155648

// Per-step barrier WITHOUT the vmcnt(0) drain __syncthreads would emit:
// LDS traffic (hb writes/reads) is ordered by lgkmcnt; global stores/loads stay
// in flight across the barrier (T4 pattern). sched_barrier fences both sides.
#define STEP_BARRIER() do {                                   \
    asm volatile("s_waitcnt lgkmcnt(0)" ::: "memory");        \
    __builtin_amdgcn_sched_barrier(0);                        \
    __builtin_amdgcn_s_barrier();                             \
    __builtin_amdgcn_sched_barrier(0);                        \
} while (0)

__device__ __forceinline__ float sgf(float x) {
    return __builtin_amdgcn_rcpf(1.f + __builtin_amdgcn_exp2f(-1.44269504089f * x));
}
__device__ __forceinline__ float thf(float x) {
    return 2.f * __builtin_amdgcn_rcpf(1.f + __builtin_amdgcn_exp2f(-2.88539008178f * x)) - 1.f;
}

// Weight fragment storage classes, f = q*8 + kt, q = jt*4+g (0..15), kt 0..7:
//   kt 0..3            -> AGPR  w_a[q*4+kt]   (64 frags, 256 AGPRs)
//   kt 4               -> ARCH  w_v[q]        (16 frags)
//   kt 5, q < 14       -> ARCH  w_v[16+q]     (14 frags)
//   kt 5, q >= 14      -> LDS   idx 32+(q-14) (2 frags)
//   kt 6,7             -> LDS   idx q*2+(kt-6)(32 frags)

// ---------------- setup kernels ----------------

__global__ void build_t0p(const float* __restrict__ emb, const float* __restrict__ wih0,
                          const float* __restrict__ bih0, const float* __restrict__ bhh0,
                          f16* __restrict__ t0p) {
    int v = blockIdx.x, hid = threadIdx.x;
    __shared__ float e[8];
    if (hid < 8) e[hid] = emb[v * 8 + hid];
    __syncthreads();
    f16x4 o;
    #pragma unroll
    for (int g = 0; g < 4; ++g) {
        int n = g * 256 + hid;
        float s = bih0[n] + bhh0[n];
        #pragma unroll
        for (int k = 0; k < 8; ++k) s += e[k] * wih0[n * 8 + k];
        o[g] = (f16)s;
    }
    *(f16x4*)&t0p[((size_t)v * 256 + hid) * 4] = o;
}

__global__ void pack_rw(const float* __restrict__ W, f16* __restrict__ Wp) {
    int gid = blockIdx.x * 256 + threadIdx.x;   // 32768
    int l = gid & 63, f = (gid >> 6) & 127, w = gid >> 13;
    int kt = f & 7, g = (f >> 3) & 3, jt = f >> 5;
    int n = g * 256 + w * 64 + jt * 16 + (l & 15);
    int k = kt * 32 + (l >> 4) * 8;
    f16x8 v;
    #pragma unroll
    for (int e = 0; e < 8; ++e) v[e] = (f16)W[n * 256 + k + e];
    *(f16x8*)&Wp[(size_t)gid * 8] = v;
}

__global__ void pack_fc(const float* __restrict__ Wfc, f16* __restrict__ Wp) {
    int gid = blockIdx.x * 256 + threadIdx.x;   // 3072
    int l = gid & 63, kt = (gid >> 6) & 7, nt = gid >> 9;
    int n = nt * 16 + (l & 15);
    int k = kt * 32 + (l >> 4) * 8;
    f16x8 v;
    #pragma unroll
    for (int e = 0; e < 8; ++e) v[e] = (n < NV) ? (f16)Wfc[n * 256 + k + e] : (f16)0.f;
    *(f16x8*)&Wp[(size_t)gid * 8] = v;
}

// ---------------- recurrent chunk body, M=2 rows per block ----------------
template<int LAYER>
__device__ __forceinline__ void rnn_body(const f16* __restrict__ Wp, const int* __restrict__ x,
                                         const f16* __restrict__ T0p, const f16* __restrict__ xgc,
                                         f16* __restrict__ hdump, float* __restrict__ cst,
                                         f16* __restrict__ hst, int t0, int bp, char* smem) {
    f16* hb = (f16*)smem;   // 2 x 4096 f16
    const int tid = threadIdx.x;
    const int w = tid >> 6, l = tid & 63, l15 = l & 15, lq = l >> 4;
    const int R0 = bp * 2;

    const f16* wgl = Wp + ((size_t)w * 128) * 512 + l * 8;
    f16* wlds = (f16*)(smem + 16384 + w * 34816);

    #pragma unroll
    for (int fi = 0; fi < 34; ++fi) {
        int f = (fi < 32) ? ((fi >> 1) * 8 + 6 + (fi & 1)) : ((14 + (fi - 32)) * 8 + 5);
        *(f16x8*)&wlds[fi * 512 + l * 8] = *(const f16x8*)&wgl[(size_t)f * 512];
    }

    f32x4 w_a[64];
    #pragma unroll
    for (int q = 0; q < 16; ++q)
        #pragma unroll
        for (int kt = 0; kt < 4; ++kt)
            w_a[q * 4 + kt] = *(const f32x4*)&wgl[(size_t)(q * 8 + kt) * 512];
    #pragma unroll
    for (int i = 0; i < 64; ++i) asm volatile("" : "+a"(w_a[i]));

    f32x4 w_v[30];
    #pragma unroll
    for (int q = 0; q < 16; ++q) w_v[q] = *(const f32x4*)&wgl[(size_t)(q * 8 + 4) * 512];
    #pragma unroll
    for (int q = 0; q < 14; ++q) w_v[16 + q] = *(const f32x4*)&wgl[(size_t)(q * 8 + 5) * 512];
    #pragma unroll
    for (int i = 0; i < 30; ++i) asm volatile("" : "+v"(w_v[i]));

    #pragma unroll
    for (int i = 0; i < 4; ++i) *(uint4*)(smem + tid * 64 + i * 16) = (uint4){0, 0, 0, 0};
    __syncthreads();

    float c[8];
    #pragma unroll
    for (int i = 0; i < 8; ++i) c[i] = 0.f;
    if (t0 > 0) {
        #pragma unroll
        for (int i = 0; i < 2; ++i) {
            int idx = tid + i * 256;
            int r = idx >> 8, hid = idx & 255;
            hb[r * 256 + (hid ^ (32 * r))] = hst[(size_t)bp * 512 + r * 256 + hid];
        }
        if (lq == 0) {
            const float* cp = cst + (((size_t)bp * 4 + w) * 16 + l15) * 8;
            #pragma unroll
            for (int i = 0; i < 8; ++i) c[i] = cp[i];
        }
    }
    __syncthreads();

    // iv prologue: (s=0, jt=0)
    f16x4 ivc0 = {}, ivc1 = {};
    int xv0 = 0, xv1 = 0, xvn0 = 0, xvn1 = 0;
    if (lq == 0) {
        const int hid0 = w * 64 + l15;
        if constexpr (LAYER == 0) {
            xv0 = x[(R0 + 0) * NS + t0];
            xv1 = x[(R0 + 1) * NS + t0];
            ivc0 = *(const f16x4*)&T0p[((size_t)xv0 * 256 + hid0) * 4];
            ivc1 = *(const f16x4*)&T0p[((size_t)xv1 * 256 + hid0) * 4];
        } else {
            ivc0 = *(const f16x4*)&xgc[((size_t)(R0 + 0) * 256 + hid0) * 4];
            ivc1 = *(const f16x4*)&xgc[((size_t)(R0 + 1) * 256 + hid0) * 4];
        }
    }

    for (int s = 0; s < TC; ++s) {
        const int t = t0 + s;
        const int rb = (s & 1) * 4096, wb = rb ^ 4096;

        // A-fragments of h(t-1) — critical path, issue first
        f16x8 a[8];
        #pragma unroll
        for (int kt = 0; kt < 8; ++kt)
            a[kt] = *(const f16x8*)&hb[rb + l15 * 256 + ((kt * 32 + lq * 8) ^ (32 * (l15 & 7)))];

        // batched dump of h(t-1) from hb[rb]: stores issue NOW and retire under
        // the MFMA phase; they no longer meet any barrier drain (raw s_barrier)
        if (s > 0) {
            #pragma unroll
            for (int i = 0; i < 2; ++i) {
                int idx = tid + i * 256;
                int r = idx >> 8, hid = idx & 255;
                hdump[((size_t)(s - 1) * 256 + R0 + r) * 256 + hid] =
                    hb[rb + r * 256 + (hid ^ (32 * r))];
            }
        }

        if constexpr (LAYER == 0) {
            if (lq == 0) {
                int tn = (t + 1 < NS) ? t + 1 : NS - 1;
                xvn0 = x[(R0 + 0) * NS + tn];
                xvn1 = x[(R0 + 1) * NS + tn];
            }
        }

        #pragma unroll
        for (int jt = 0; jt < 4; ++jt) {
            f16x4 ivn0 = {}, ivn1 = {};
            if (lq == 0) {
                if (jt < 3) {
                    const int hidN = w * 64 + (jt + 1) * 16 + l15;
                    if constexpr (LAYER == 0) {
                        ivn0 = *(const f16x4*)&T0p[((size_t)xv0 * 256 + hidN) * 4];
                        ivn1 = *(const f16x4*)&T0p[((size_t)xv1 * 256 + hidN) * 4];
                    } else {
                        ivn0 = *(const f16x4*)&xgc[(((size_t)s * 256 + R0 + 0) * 256 + hidN) * 4];
                        ivn1 = *(const f16x4*)&xgc[(((size_t)s * 256 + R0 + 1) * 256 + hidN) * 4];
                    }
                } else {
                    const int sn = (s + 1 < TC) ? s + 1 : s;
                    const int hid0 = w * 64 + l15;
                    if constexpr (LAYER == 0) {
                        ivn0 = *(const f16x4*)&T0p[((size_t)xvn0 * 256 + hid0) * 4];
                        ivn1 = *(const f16x4*)&T0p[((size_t)xvn1 * 256 + hid0) * 4];
                    } else {
                        ivn0 = *(const f16x4*)&xgc[(((size_t)sn * 256 + R0 + 0) * 256 + hid0) * 4];
                        ivn1 = *(const f16x4*)&xgc[(((size_t)sn * 256 + R0 + 1) * 256 + hid0) * 4];
                    }
                }
            }

            f32x4 acc[4];
            #pragma unroll
            for (int g = 0; g < 4; ++g) acc[g] = (f32x4){0.f, 0.f, 0.f, 0.f};

            #pragma unroll
            for (int kt = 0; kt < 8; ++kt) {
                #pragma unroll
                for (int g = 0; g < 4; ++g) {
                    const int q = jt * 4 + g;
                    f16x8 bfr;
                    if (kt < 4)                 bfr = __builtin_bit_cast(f16x8, w_a[q * 4 + kt]);
                    else if (kt == 4)           bfr = __builtin_bit_cast(f16x8, w_v[q]);
                    else if (kt == 5 && q < 14) bfr = __builtin_bit_cast(f16x8, w_v[16 + q]);
                    else if (kt == 5)           bfr = *(const f16x8*)&wlds[(32 + (q - 14)) * 512 + l * 8];
                    else                        bfr = *(const f16x8*)&wlds[(q * 2 + (kt - 6)) * 512 + l * 8];
                    acc[g] = __builtin_amdgcn_mfma_f32_16x16x32_f16(a[kt], bfr, acc[g], 0, 0, 0);
                }
            }

            // elementwise: 2 rows, lq==0 lanes; LDS write only (no global store)
            if (lq == 0) {
                #pragma unroll
                for (int r = 0; r < 2; ++r) {
                    const f16x4 iv = r ? ivc1 : ivc0;
                    float gi = acc[0][r] + (float)iv[0];
                    float gf = acc[1][r] + (float)iv[1];
                    float gg = acc[2][r] + (float)iv[2];
                    float go = acc[3][r] + (float)iv[3];
                    float si = sgf(gi), sf = sgf(gf), tg = thf(gg), so = sgf(go);
                    const int ci = jt * 2 + r;
                    c[ci] = sf * c[ci] + si * tg;
                    float h = so * thf(c[ci]);
                    const int hid = w * 64 + jt * 16 + l15;
                    hb[wb + r * 256 + (hid ^ (32 * r))] = (f16)h;
                }
            }
            ivc0 = ivn0; ivc1 = ivn1;
            if constexpr (LAYER == 0) {
                if (jt == 3) { xv0 = xvn0; xv1 = xvn1; }
            }
        }
        STEP_BARRIER();
    }
    // epilogue: final h in buffer 0 (TC even): dump slot TC-1 + save state
    if (lq == 0) {
        float* cp = cst + (((size_t)bp * 4 + w) * 16 + l15) * 8;
        #pragma unroll
        for (int i = 0; i < 8; ++i) cp[i] = c[i];
    }
    #pragma unroll
    for (int i = 0; i < 2; ++i) {
        int idx = tid + i * 256;
        int r = idx >> 8, hid = idx & 255;
        f16 hv = hb[r * 256 + (hid ^ (32 * r))];
        hdump[((size_t)(TC - 1) * 256 + R0 + r) * 256 + hid] = hv;
        hst[(size_t)bp * 512 + r * 256 + hid] = hv;
    }
}

// Co-launched: blocks 0-127 = layer0 chunk k, blocks 128-255 = layer1 chunk k-1.
__global__ __launch_bounds__(256, 1)
void fused_rnn(const f16* __restrict__ Wp0, const f16* __restrict__ Wp1,
               const int* __restrict__ x, const f16* __restrict__ T0p,
               const f16* __restrict__ xgc, f16* __restrict__ h1g, f16* __restrict__ h2g,
               float* __restrict__ cst0, float* __restrict__ cst1,
               f16* __restrict__ hst0, f16* __restrict__ hst1,
               int t0l0, int do0, int do1) {
    extern __shared__ char smem[];
    if (blockIdx.x < 128) {
        if (do0) rnn_body<0>(Wp0, x, T0p, nullptr, h1g, cst0, hst0, t0l0, blockIdx.x, smem);
    } else {
        if (do1) rnn_body<1>(Wp1, nullptr, nullptr, xgc, h2g, cst1, hst1, t0l0 - TC, blockIdx.x - 128, smem);
    }
}

// ---------------- merged aux kernel: xg1(chunk k) + fc(chunk k-1) ----------------
__device__ __forceinline__ void xg1_body(const f16* __restrict__ h1g, const f16* __restrict__ Wxp,
                                         const float* __restrict__ bih1, const float* __restrict__ bhh1,
                                         f16* __restrict__ xgc, int bid) {
    const int tid = threadIdx.x, wv = tid >> 6, l = tid & 63, l15 = l & 15, lq = l >> 4;
    const int bg = bid & 15, ns = (bid >> 4) & 3, tcc = bid >> 6;

    f16x8 bf[4][8];
    #pragma unroll
    for (int g = 0; g < 4; ++g)
        #pragma unroll
        for (int kt = 0; kt < 8; ++kt)
            bf[g][kt] = *(const f16x8*)&Wxp[((size_t)(ns * 128 + (wv * 4 + g) * 8 + kt) * 64 + l) * 8];
    float bs[4];
    #pragma unroll
    for (int g = 0; g < 4; ++g) {
        int n = g * 256 + ns * 64 + wv * 16 + l15;
        bs[g] = bih1[n] + bhh1[n];
    }
    const int hid = ns * 64 + wv * 16 + l15;

    for (int tt = 0; tt < 16; ++tt) {
        int s = tcc * 16 + tt;
        f16x8 a[8];
        #pragma unroll
        for (int kt = 0; kt < 8; ++kt)
            a[kt] = *(const f16x8*)&h1g[((size_t)s * 256 + bg * 16 + l15) * 256 + kt * 32 + lq * 8];
        f32x4 acc[4];
        #pragma unroll
        for (int g = 0; g < 4; ++g) acc[g] = (f32x4){bs[g], bs[g], bs[g], bs[g]};
        #pragma unroll
        for (int kt = 0; kt < 8; ++kt)
            #pragma unroll
            for (int g = 0; g < 4; ++g)
                acc[g] = __builtin_amdgcn_mfma_f32_16x16x32_f16(a[kt], bf[g][kt], acc[g], 0, 0, 0);
        #pragma unroll
        for (int r = 0; r < 4; ++r) {
            f16x4 o = { (f16)acc[0][r], (f16)acc[1][r], (f16)acc[2][r], (f16)acc[3][r] };
            int row = bg * 16 + lq * 4 + r;
            *(f16x4*)&xgc[(((size_t)s * 256 + row) * 256 + hid) * 4] = o;
        }
    }
}

__device__ __forceinline__ void fc_body(const f16* __restrict__ h2g, const f16* __restrict__ Wfcp,
                                        const float* __restrict__ bfc, float* __restrict__ out,
                                        int t0, int bid) {
    const int tid = threadIdx.x, wv = tid >> 6, l = tid & 63, l15 = l & 15, lq = l >> 4;
    const int bg = bid & 15, tb = bid >> 4;
    const int s = tb * 4 + wv;

    f16x8 bf[6][8];
    #pragma unroll
    for (int nt = 0; nt < 6; ++nt)
        #pragma unroll
        for (int kt = 0; kt < 8; ++kt)
            bf[nt][kt] = *(const f16x8*)&Wfcp[((size_t)(nt * 8 + kt) * 64 + l) * 8];
    float bb[6];
    #pragma unroll
    for (int nt = 0; nt < 6; ++nt) {
        int n = nt * 16 + l15;
        bb[nt] = (n < NV) ? bfc[n] : 0.f;
    }

    f16x8 a[8];
    #pragma unroll
    for (int kt = 0; kt < 8; ++kt)
        a[kt] = *(const f16x8*)&h2g[((size_t)s * 256 + bg * 16 + l15) * 256 + kt * 32 + lq * 8];
    f32x4 acc[6];
    #pragma unroll
    for (int nt = 0; nt < 6; ++nt) acc[nt] = (f32x4){bb[nt], bb[nt], bb[nt], bb[nt]};
    #pragma unroll
    for (int kt = 0; kt < 8; ++kt)
        #pragma unroll
        for (int nt = 0; nt < 6; ++nt)
            acc[nt] = __builtin_amdgcn_mfma_f32_16x16x32_f16(a[kt], bf[nt][kt], acc[nt], 0, 0, 0);
    #pragma unroll
    for (int nt = 0; nt < 6; ++nt) {
        int n = nt * 16 + l15;
        if (n < NV) {
            #pragma unroll
            for (int r = 0; r < 4; ++r)
                out[((size_t)(bg * 16 + lq * 4 + r) * NS + (t0 + s)) * NV + n] = acc[nt][r];
        }
    }
}

__global__ __launch_bounds__(256, 1)
void aux_kernel(const f16* __restrict__ h1g, const f16* __restrict__ Wxp,
                const float* __restrict__ bih1, const float* __restrict__ bhh1,
                f16* __restrict__ xgc, const f16* __restrict__ h2g,
                const f16* __restrict__ Wfcp, const float* __restrict__ bfc,
                float* __restrict__ out, int t0fc, int doXg, int doFc) {
    if (blockIdx.x < 256) {
        if (doXg) xg1_body(h1g, Wxp, bih1, bhh1, xgc, blockIdx.x);
    } else {
        if (doFc) fc_body(h2g, Wfcp, bfc, out, t0fc, blockIdx.x - 256);
    }
}

extern "C" void kernel_launch(void* const* d_in, const int* in_sizes, int n_in,
                              void* d_out, int out_size, void* d_ws, size_t ws_size,
                              hipStream_t stream) {
    const int*   x    = (const int*)  d_in[0];
    const float* emb  = (const float*)d_in[1];
    const float* wih0 = (const float*)d_in[2];
    const float* whh0 = (const float*)d_in[3];
    const float* bih0 = (const float*)d_in[4];
    const float* bhh0 = (const float*)d_in[5];
    const float* wih1 = (const float*)d_in[6];
    const float* whh1 = (const float*)d_in[7];
    const float* bih1 = (const float*)d_in[8];
    const float* bhh1 = (const float*)d_in[9];
    const float* wfc  = (const float*)d_in[10];
    const float* bfc  = (const float*)d_in[11];
    float* out = (float*)d_out;

    char* ws = (char*)d_ws;
    f16*   Wp0  = (f16*)(ws + 0);             //  524288
    f16*   Wp1  = (f16*)(ws + 524288);        //  524288
    f16*   Wxp  = (f16*)(ws + 1048576);       //  524288
    f16*   Wfcp = (f16*)(ws + 1572864);       //   49152
    f16*   T0p  = (f16*)(ws + 1622016);       //  184320
    float* cst0 = (float*)(ws + 1806336);     //  262144
    float* cst1 = (float*)(ws + 2068480);     //  262144
    f16*   hst0 = (f16*)(ws + 2330624);       //  131072
    f16*   hst1 = (f16*)(ws + 2461696);       //  131072
    const size_t base = 2592768;

    f16* h1g = (f16*)(ws + base);
    f16* xgc = (f16*)(ws + base + (size_t)TC * 131072);
    f16* h2g = (f16*)(ws + base + (size_t)TC * 131072 + (size_t)TC * 524288);

    hipFuncSetAttribute(reinterpret_cast<const void*>(fused_rnn),
                        hipFuncAttributeMaxDynamicSharedMemorySize, R_LDS_BYTES);

    build_t0p<<<90, 256, 0, stream>>>(emb, wih0, bih0, bhh0, T0p);
    pack_rw<<<128, 256, 0, stream>>>(whh0, Wp0);
    pack_rw<<<128, 256, 0, stream>>>(whh1, Wp1);
    pack_rw<<<128, 256, 0, stream>>>(wih1, Wxp);
    pack_fc<<<12, 256, 0, stream>>>(wfc, Wfcp);

    const int NCH = NS / TC;   // 8
    for (int k = 0; k <= NCH; ++k) {
        fused_rnn<<<256, 256, R_LDS_BYTES, stream>>>(Wp0, Wp1, x, T0p, xgc, h1g, h2g,
                                                     cst0, cst1, hst0, hst1,
                                                     k * TC, (int)(k < NCH), (int)(k > 0));
        aux_kernel<<<512, 256, 0, stream>>>(h1g, Wxp, bih1, bhh1, xgc, h2g, Wfcp, bfc,
                                            out, (k - 1) * TC, (int)(k < NCH), (int)(k > 0));
    }
}